// Round 2
// baseline (494.205 us; speedup 1.0000x reference)
//
#include <hip/hip_runtime.h>

// EmbeddingDistance: out[b] = 1 - dot(mean_i norm(x1[b,i,:]), mean_j norm(x2[b,j,:]))
// x1, x2: (16, 4096, 256) fp32.  134 MB read exactly once.
// v3: DPP-based 16-lane norm reduce (4 dependent VALU ops, zero ds ops in the
//     main loop) + single fused kernel (per-batch atomic counter, mod-128
//     trick so no counter reset / memset is ever needed).

constexpr int D = 256;            // embedding dim
constexpr int S = 4096;           // segments (rows) per batch
constexpr int B = 16;             // batches
constexpr int BLOCKS_PER_PAIR = 64;
constexpr int WAVES_PER_BLOCK = 4;              // 256 threads
constexpr int WAVES_PER_PAIR  = BLOCKS_PER_PAIR * WAVES_PER_BLOCK;  // 256
constexpr int ROWS_PER_WAVE   = S / WAVES_PER_PAIR;                 // 16
constexpr int NPAIR = 2 * B;                                        // 32
constexpr int NBLK1 = NPAIR * BLOCKS_PER_PAIR;                      // 2048
constexpr int BLOCKS_PER_BATCH = 2 * BLOCKS_PER_PAIR;               // 128
constexpr float EPS2 = 1e-16f;    // eps^2 for the norm clamp

// Per-batch completion counters.  mod-128 trick: exactly one block out of
// every 128 increments sees (old & 127)==127, regardless of initial value —
// so no reset between launches, graph replays, or rocprof replays.
__device__ unsigned g_ctrs[B];

// ---- DPP helpers: reduction across a 16-lane DPP "row", all-VALU.
template <int CTRL>
__device__ __forceinline__ float dpp_add(float x) {
    int y = __builtin_amdgcn_update_dpp(0, __float_as_int(x), CTRL, 0xF, 0xF, true);
    return x + __int_as_float(y);
}
__device__ __forceinline__ float row16_allsum(float ss) {
    ss = dpp_add<0xB1>(ss);   // quad_perm(1,0,3,2): xor1
    ss = dpp_add<0x4E>(ss);   // quad_perm(2,3,0,1): xor2
    ss = dpp_add<0x141>(ss);  // row_half_mirror: other quad within 8
    ss = dpp_add<0x140>(ss);  // row_mirror: other 8-half within 16
    return ss;                // all 16 lanes hold the full sum
}

// ---- MODE 0: fused (partials in ws, finalize in-kernel).
// ---- MODE 1: atomic fallback (sums [NPAIR][D], pre-zeroed; separate finalize).
template <int MODE>
__global__ __launch_bounds__(256, 8) void embdist_kernel(
    const float* __restrict__ x1, const float* __restrict__ x2,
    float* __restrict__ partials /* [NBLK1][D] when MODE==0 */,
    float* __restrict__ sums     /* [NPAIR][D] when MODE==1 */,
    float* __restrict__ out      /* [B], written when MODE==0 */)
{
    const int pair = blockIdx.x / BLOCKS_PER_PAIR;      // 0..31
    const int blk  = blockIdx.x % BLOCKS_PER_PAIR;      // 0..63
    const int w    = threadIdx.x >> 6;                  // 0..3
    const int lane = threadIdx.x & 63;
    const int sub  = lane & 15;                         // dim-slice owner
    const int g    = lane >> 4;                         // row-in-group 0..3
    const int wv   = blk * WAVES_PER_BLOCK + w;         // 0..255 within pair

    const float* __restrict__ src = (pair & 1) ? x2 : x1;
    src += (size_t)(pair >> 1) * S * D;
    // wave owns rows [wv*16, wv*16+16); lane's base: row (wv*16+g), float4 #sub
    const float* __restrict__ lbase =
        src + (size_t)(wv * ROWS_PER_WAVE + g) * D + sub * 4;

    float4 a0 = make_float4(0.f, 0.f, 0.f, 0.f);
    float4 a1 = a0, a2 = a0, a3 = a0;
    float4 va0, va1, va2, va3, vb0, vb1, vb2, vb3;

#define LOADV(v0,v1,v2,v3, i)  do {                     \
    const float* p_ = lbase + (size_t)(i) * 4 * D;      \
    v0 = *(const float4*)(p_ +   0);                    \
    v1 = *(const float4*)(p_ +  64);                    \
    v2 = *(const float4*)(p_ + 128);                    \
    v3 = *(const float4*)(p_ + 192); } while (0)

#define STEPV(v0,v1,v2,v3) do {                                        \
    float ss = v0.x*v0.x + v0.y*v0.y + v0.z*v0.z + v0.w*v0.w           \
             + v1.x*v1.x + v1.y*v1.y + v1.z*v1.z + v1.w*v1.w           \
             + v2.x*v2.x + v2.y*v2.y + v2.z*v2.z + v2.w*v2.w           \
             + v3.x*v3.x + v3.y*v3.y + v3.z*v3.z + v3.w*v3.w;          \
    ss = row16_allsum(ss);                                             \
    const float sc_ = rsqrtf(fmaxf(ss, EPS2));                         \
    a0.x += v0.x*sc_; a0.y += v0.y*sc_; a0.z += v0.z*sc_; a0.w += v0.w*sc_; \
    a1.x += v1.x*sc_; a1.y += v1.y*sc_; a1.z += v1.z*sc_; a1.w += v1.w*sc_; \
    a2.x += v2.x*sc_; a2.y += v2.y*sc_; a2.z += v2.z*sc_; a2.w += v2.w*sc_; \
    a3.x += v3.x*sc_; a3.y += v3.y*sc_; a3.z += v3.z*sc_; a3.w += v3.w*sc_; \
  } while (0)

    // 4 steps of 4 rows, double-buffered.
    LOADV(va0,va1,va2,va3, 0);
    LOADV(vb0,vb1,vb2,vb3, 1);
    STEPV(va0,va1,va2,va3);
    LOADV(va0,va1,va2,va3, 2);
    STEPV(vb0,vb1,vb2,vb3);
    LOADV(vb0,vb1,vb2,vb3, 3);
    STEPV(va0,va1,va2,va3);
    STEPV(vb0,vb1,vb2,vb3);

#undef LOADV
#undef STEPV

    // Per-wave, per-row-group partials to LDS; block reduce sums all 16.
    // Pad inner dim to 260 so the g-strided float4 stores stay ~2-way.
    __shared__ float lds[WAVES_PER_BLOCK][4][260];
    *(float4*)&lds[w][g][4 * sub      ] = a0;   // acc m covers dims 4*sub+64*m
    *(float4*)&lds[w][g][4 * sub +  64] = a1;
    *(float4*)&lds[w][g][4 * sub + 128] = a2;
    *(float4*)&lds[w][g][4 * sub + 192] = a3;
    __syncthreads();

    const int t = threadIdx.x;
    float val = 0.f;
    #pragma unroll
    for (int ww = 0; ww < WAVES_PER_BLOCK; ++ww)
        #pragma unroll
        for (int gg = 0; gg < 4; ++gg)
            val += lds[ww][gg][t];

    if (MODE == 1) {
        atomicAdd(&sums[(size_t)pair * D + t], val);
        return;
    }

    // ---- MODE 0: fused finalize.
    partials[(size_t)blockIdx.x * D + t] = val;
    __threadfence();                  // release: make partials agent-visible
    __syncthreads();                  // all threads' stores+fences done
    __shared__ unsigned old_s;
    const int b = pair >> 1;
    if (t == 0) old_s = atomicAdd(&g_ctrs[b], 1u);
    __syncthreads();

    if ((old_s & (BLOCKS_PER_BATCH - 1)) == (BLOCKS_PER_BATCH - 1)) {
        // Last of the 128 blocks of batch b: all other partials are visible
        // after an acquire fence.
        __threadfence();
        const float* p1 = partials + (size_t)(2 * b) * BLOCKS_PER_PAIR * D + t;
        const float* p2 = p1 + (size_t)BLOCKS_PER_PAIR * D;
        float s1 = 0.f, s2 = 0.f;
        #pragma unroll 8
        for (int k = 0; k < BLOCKS_PER_PAIR; ++k) {
            s1 += p1[(size_t)k * D];
            s2 += p2[(size_t)k * D];
        }
        float dsum = s1 * s2;
        #pragma unroll
        for (int m = 1; m < 64; m <<= 1) dsum += __shfl_xor(dsum, m, 64);
        __shared__ float r[WAVES_PER_BLOCK];
        if (lane == 0) r[w] = dsum;
        __syncthreads();
        if (t == 0) {
            const float inv = 1.0f / ((float)S * (float)S);
            out[b] = 1.0f - (r[0] + r[1] + r[2] + r[3]) * inv;
        }
    }
}

// ---- Fallback finalize (atomic path): sums are already fully reduced.
__global__ __launch_bounds__(64) void finalize_kernel(
    const float* __restrict__ sums, float* __restrict__ out)
{
    const int b = blockIdx.x;
    const int lane = threadIdx.x;
    const float4 a = *(const float4*)(sums + (size_t)(2 * b + 0) * D + lane * 4);
    const float4 c = *(const float4*)(sums + (size_t)(2 * b + 1) * D + lane * 4);
    float d = a.x * c.x + a.y * c.y + a.z * c.z + a.w * c.w;
    #pragma unroll
    for (int m = 1; m < 64; m <<= 1) d += __shfl_xor(d, m, 64);
    if (lane == 0) {
        const float inv = 1.0f / ((float)S * (float)S);
        out[b] = 1.0f - d * inv;
    }
}

extern "C" void kernel_launch(void* const* d_in, const int* in_sizes, int n_in,
                              void* d_out, int out_size, void* d_ws, size_t ws_size,
                              hipStream_t stream) {
    const float* x1 = (const float*)d_in[0];
    const float* x2 = (const float*)d_in[1];
    float* out = (float*)d_out;
    float* ws = (float*)d_ws;

    const size_t partial_bytes = (size_t)NBLK1 * D * sizeof(float);   // 2 MB
    if (ws_size >= partial_bytes) {
        embdist_kernel<0><<<NBLK1, 256, 0, stream>>>(x1, x2, ws, nullptr, out);
    } else {
        hipMemsetAsync(ws, 0, (size_t)NPAIR * D * sizeof(float), stream);
        embdist_kernel<1><<<NBLK1, 256, 0, stream>>>(x1, x2, nullptr, ws, out);
        finalize_kernel<<<B, 64, 0, stream>>>(ws, out);
    }
}

// Round 3
// 143.981 us; speedup vs baseline: 3.4324x; 3.4324x over previous
//
#include <hip/hip_runtime.h>

// EmbeddingDistance: out[b] = 1 - dot(mean_i norm(x1[b,i,:]), mean_j norm(x2[b,j,:]))
// x1, x2: (16, 4096, 256) fp32.  134 MB read exactly once.
// v4: revert v3's fused finalize (per-block __threadfence = per-block L2
//     writeback on gfx950 -> 9x regression).  Two kernels again.
//     Kernel 1: one-shot issue of all 16 dwordx4 loads per wave (16 KB in
//     flight), then 4 INDEPENDENT DPP reduce chains -> latency overlap.
//     DPP (VALU) replaces shfl (LDS pipe) for the 16-lane norm reduce.

constexpr int D = 256;            // embedding dim
constexpr int S = 4096;           // segments (rows) per batch
constexpr int B = 16;             // batches
constexpr int BLOCKS_PER_PAIR = 64;
constexpr int WAVES_PER_BLOCK = 4;              // 256 threads
constexpr int WAVES_PER_PAIR  = BLOCKS_PER_PAIR * WAVES_PER_BLOCK;  // 256
constexpr int ROWS_PER_WAVE   = S / WAVES_PER_PAIR;                 // 16
constexpr int NPAIR = 2 * B;                                        // 32
constexpr int NBLK1 = NPAIR * BLOCKS_PER_PAIR;                      // 2048
constexpr float EPS2 = 1e-16f;    // eps^2 for the norm clamp

// ---- DPP helpers: reduction across a 16-lane DPP "row", all-VALU.
template <int CTRL>
__device__ __forceinline__ float dpp_add(float x) {
    int y = __builtin_amdgcn_update_dpp(0, __float_as_int(x), CTRL, 0xF, 0xF, true);
    return x + __int_as_float(y);
}
__device__ __forceinline__ float row16_allsum(float ss) {
    ss = dpp_add<0xB1>(ss);   // quad_perm(1,0,3,2): xor1
    ss = dpp_add<0x4E>(ss);   // quad_perm(2,3,0,1): xor2
    ss = dpp_add<0x141>(ss);  // row_half_mirror
    ss = dpp_add<0x140>(ss);  // row_mirror
    return ss;                // all 16 lanes hold the full sum
}

// ---- Kernel 1: wave owns 16 consecutive rows.  lane = (g<<4)|sub:
// g = row-in-group (0..3), sub = dim-slice; lane's 4 float4s cover dims
// {4sub, 4sub+64, 4sub+128, 4sub+192}..+3.  All 16 loads issued before any
// use; 4 independent sumsq/DPP chains overlap their latencies.
template <bool USE_PARTIALS>
__global__ __launch_bounds__(256) void row_norm_sum_kernel(
    const float* __restrict__ x1, const float* __restrict__ x2,
    float* __restrict__ sums /* USE_PARTIALS ? [NBLK1][D] : [NPAIR][D] */)
{
    const int pair = blockIdx.x / BLOCKS_PER_PAIR;      // 0..31
    const int blk  = blockIdx.x % BLOCKS_PER_PAIR;      // 0..63
    const int w    = threadIdx.x >> 6;                  // 0..3
    const int lane = threadIdx.x & 63;
    const int sub  = lane & 15;                         // dim-slice owner
    const int g    = lane >> 4;                         // row-in-group 0..3
    const int wv   = blk * WAVES_PER_BLOCK + w;         // 0..255 within pair

    const float* __restrict__ src = (pair & 1) ? x2 : x1;
    src += (size_t)(pair >> 1) * S * D;
    // lane's base: row (wv*16 + g), float4 #sub
    const float* __restrict__ lbase =
        src + (size_t)(wv * ROWS_PER_WAVE + g) * D + sub * 4;

    // ---- issue ALL 16 loads (16 KB/wave in flight) before any consumption.
    float4 vv[4][4];                         // [row-step i][dim-slice j]
    #pragma unroll
    for (int i = 0; i < 4; ++i) {
        const float* p_ = lbase + (size_t)i * 4 * D;   // rows g, g+4, g+8, g+12
        vv[i][0] = *(const float4*)(p_ +   0);
        vv[i][1] = *(const float4*)(p_ +  64);
        vv[i][2] = *(const float4*)(p_ + 128);
        vv[i][3] = *(const float4*)(p_ + 192);
    }

    // ---- 4 independent sumsq values ...
    float ss[4];
    #pragma unroll
    for (int i = 0; i < 4; ++i) {
        float s = 0.f;
        #pragma unroll
        for (int j = 0; j < 4; ++j)
            s += vv[i][j].x * vv[i][j].x + vv[i][j].y * vv[i][j].y
               + vv[i][j].z * vv[i][j].z + vv[i][j].w * vv[i][j].w;
        ss[i] = s;
    }
    // ---- ... reduced by 4 independent 4-deep DPP chains (latencies overlap).
    #pragma unroll
    for (int i = 0; i < 4; ++i) ss[i] = row16_allsum(ss[i]);

    float sc[4];
    #pragma unroll
    for (int i = 0; i < 4; ++i) sc[i] = rsqrtf(fmaxf(ss[i], EPS2));

    float4 acc[4];
    #pragma unroll
    for (int j = 0; j < 4; ++j) acc[j] = make_float4(0.f, 0.f, 0.f, 0.f);
    #pragma unroll
    for (int i = 0; i < 4; ++i) {
        #pragma unroll
        for (int j = 0; j < 4; ++j) {
            acc[j].x += vv[i][j].x * sc[i];
            acc[j].y += vv[i][j].y * sc[i];
            acc[j].z += vv[i][j].z * sc[i];
            acc[j].w += vv[i][j].w * sc[i];
        }
    }

    // ---- Per-wave, per-row-group partials to LDS; block reduce sums 16 slices.
    __shared__ float lds[WAVES_PER_BLOCK][4][260];
    *(float4*)&lds[w][g][4 * sub      ] = acc[0];
    *(float4*)&lds[w][g][4 * sub +  64] = acc[1];
    *(float4*)&lds[w][g][4 * sub + 128] = acc[2];
    *(float4*)&lds[w][g][4 * sub + 192] = acc[3];
    __syncthreads();

    const int t = threadIdx.x;
    float val = 0.f;
    #pragma unroll
    for (int ww = 0; ww < WAVES_PER_BLOCK; ++ww)
        #pragma unroll
        for (int gg = 0; gg < 4; ++gg)
            val += lds[ww][gg][t];

    if (USE_PARTIALS) {
        sums[(size_t)blockIdx.x * D + t] = val;     // no atomics, no memset
    } else {
        atomicAdd(&sums[(size_t)pair * D + t], val);
    }
}

// ---- Kernel 2 (partials path): per batch, reduce 64-block partials for both
// inputs, dot them, block-reduce, write 1 - dot/S^2.
__global__ __launch_bounds__(256) void finalize_partials_kernel(
    const float* __restrict__ partials, float* __restrict__ out)
{
    const int b = blockIdx.x;
    const int t = threadIdx.x;
    const int w = t >> 6, lane = t & 63;

    const float* p1 = partials + ((size_t)(2 * b + 0) * BLOCKS_PER_PAIR) * D + t;
    const float* p2 = partials + ((size_t)(2 * b + 1) * BLOCKS_PER_PAIR) * D + t;
    float s1 = 0.f, s2 = 0.f;
    #pragma unroll 8
    for (int k = 0; k < BLOCKS_PER_PAIR; ++k) {
        s1 += p1[(size_t)k * D];
        s2 += p2[(size_t)k * D];
    }
    float d = s1 * s2;
    #pragma unroll
    for (int m = 1; m < 64; m <<= 1) d += __shfl_xor(d, m, 64);

    __shared__ float r[WAVES_PER_BLOCK];
    if (lane == 0) r[w] = d;
    __syncthreads();
    if (t == 0) {
        const float inv = 1.0f / ((float)S * (float)S);
        out[b] = 1.0f - (r[0] + r[1] + r[2] + r[3]) * inv;
    }
}

// ---- Kernel 2 (atomic fallback path): sums are already fully reduced.
__global__ __launch_bounds__(64) void finalize_kernel(
    const float* __restrict__ sums, float* __restrict__ out)
{
    const int b = blockIdx.x;
    const int lane = threadIdx.x;
    const float4 a = *(const float4*)(sums + (size_t)(2 * b + 0) * D + lane * 4);
    const float4 c = *(const float4*)(sums + (size_t)(2 * b + 1) * D + lane * 4);
    float d = a.x * c.x + a.y * c.y + a.z * c.z + a.w * c.w;
    #pragma unroll
    for (int m = 1; m < 64; m <<= 1) d += __shfl_xor(d, m, 64);
    if (lane == 0) {
        const float inv = 1.0f / ((float)S * (float)S);
        out[b] = 1.0f - d * inv;
    }
}

extern "C" void kernel_launch(void* const* d_in, const int* in_sizes, int n_in,
                              void* d_out, int out_size, void* d_ws, size_t ws_size,
                              hipStream_t stream) {
    const float* x1 = (const float*)d_in[0];
    const float* x2 = (const float*)d_in[1];
    float* out = (float*)d_out;
    float* ws = (float*)d_ws;

    const size_t partial_bytes = (size_t)NBLK1 * D * sizeof(float);   // 2 MB
    if (ws_size >= partial_bytes) {
        row_norm_sum_kernel<true><<<NBLK1, 256, 0, stream>>>(x1, x2, ws);
        finalize_partials_kernel<<<B, 256, 0, stream>>>(ws, out);
    } else {
        hipMemsetAsync(ws, 0, (size_t)NPAIR * D * sizeof(float), stream);
        row_norm_sum_kernel<false><<<NBLK1, 256, 0, stream>>>(x1, x2, ws);
        finalize_kernel<<<B, 64, 0, stream>>>(ws, out);
    }
}